// Round 2
// baseline (671.922 us; speedup 1.0000x reference)
//
#include <hip/hip_runtime.h>

typedef unsigned short u16;
typedef __attribute__((ext_vector_type(8))) short short8;
typedef __attribute__((ext_vector_type(4))) float f32x4;

#define DEVI static __device__ __forceinline__

DEVI u16 f2bf(float f) {
  union { float f; unsigned u; } v; v.f = f;
  unsigned r = v.u + 0x7FFFu + ((v.u >> 16) & 1u);
  return (u16)(r >> 16);
}

DEVI float bf2f(u16 x) {
  union { unsigned u; float f; } v; v.u = ((unsigned)x) << 16;
  return v.f;
}

DEVI short8 pack8(float4 a, float4 b) {
  short8 v;
  v[0] = (short)f2bf(a.x); v[1] = (short)f2bf(a.y);
  v[2] = (short)f2bf(a.z); v[3] = (short)f2bf(a.w);
  v[4] = (short)f2bf(b.x); v[5] = (short)f2bf(b.y);
  v[6] = (short)f2bf(b.z); v[7] = (short)f2bf(b.w);
  return v;
}

DEVI float sigm(float x) {
  return __builtin_amdgcn_rcpf(1.f + __expf(-x));
}
DEVI float tanh_(float x) {
  // 1 - 2/(exp(2x)+1); correct limits at +-inf
  return 1.f - 2.f * __builtin_amdgcn_rcpf(__expf(2.f * x) + 1.f);
}

// ---------------------------------------------------------------------------
// Prep: transpose weights to bf16 for contiguous 16B MFMA b-fragments.
//   Ut[1024][256] <- U(256,1024)   Wt[1024][128] <- W(128,1024)
//   w2t[64][512]  <- w2_k(512,64)
// ---------------------------------------------------------------------------
__global__ __launch_bounds__(256) void k_prep(
    const float* __restrict__ W, const float* __restrict__ U,
    const float* __restrict__ w2k, u16* __restrict__ Wt,
    u16* __restrict__ Ut, u16* __restrict__ w2t) {
  int idx = blockIdx.x * 256 + threadIdx.x;
  int stride = gridDim.x * 256;
  for (int i = idx; i < 256 * 1024; i += stride) {
    int k = i >> 10, j = i & 1023;
    Ut[j * 256 + k] = f2bf(U[i]);
  }
  for (int i = idx; i < 128 * 1024; i += stride) {
    int k = i >> 10, j = i & 1023;
    Wt[j * 128 + k] = f2bf(W[i]);
  }
  for (int i = idx; i < 512 * 64; i += stride) {
    int k = i >> 6, s = i & 63;
    w2t[s * 512 + k] = f2bf(w2k[i]);
  }
}

// ---------------------------------------------------------------------------
// XW precompute: XWf = x@W + b for ALL timesteps, stored bf16 in MFMA
// C-fragment layout so the scan's acc-init is a single ushort4 load.
//   fragment tile ft = col>>4 (64 tiles of 16 cols); element (lane, r) holds
//   (batch = (lane>>4)*4+r, col = ft*16 + (lane&15)).
//   XWf[((t*8+bg)*64 + ft)*256 + lane*4 + r]
// Grid: 512 blocks = (t 0..63) x (bg 0..7), 512 threads (8 waves).
// ---------------------------------------------------------------------------
__global__ __launch_bounds__(512) void k_xw(
    const float* __restrict__ data, const float* __restrict__ bias,
    const u16* __restrict__ Wt, u16* __restrict__ XWf) {
  __shared__ u16 Xs[16][136];
  const int tid = threadIdx.x;
  const int lane = tid & 63;
  const int w = tid >> 6;
  const int l15 = lane & 15;
  const int l4 = lane >> 4;
  const int t = blockIdx.x >> 3, bg = blockIdx.x & 7, b0 = bg << 4;

  if (tid < 256) {
    int row = tid >> 4, cb = (tid & 15) * 8;
    const float4* p = reinterpret_cast<const float4*>(
        &data[(size_t)(b0 + row) * 8192 + t * 128 + cb]);
    float4 va = p[0], vb = p[1];
    *reinterpret_cast<short8*>(&Xs[row][cb]) = pack8(va, vb);
  }
  __syncthreads();

  f32x4 acc[8];
#pragma unroll
  for (int ct = 0; ct < 8; ++ct) {
    float bv = bias[w * 128 + ct * 16 + l15];
    acc[ct] = (f32x4){bv, bv, bv, bv};
  }
#pragma unroll
  for (int kk = 0; kk < 4; ++kk) {
    short8 af = *reinterpret_cast<const short8*>(&Xs[l15][kk * 32 + l4 * 8]);
#pragma unroll
    for (int ct = 0; ct < 8; ++ct) {
      const int col = w * 128 + ct * 16 + l15;
      short8 bf =
          *reinterpret_cast<const short8*>(&Wt[col * 128 + kk * 32 + l4 * 8]);
      acc[ct] = __builtin_amdgcn_mfma_f32_16x16x32_bf16(af, bf, acc[ct], 0, 0, 0);
    }
  }
#pragma unroll
  for (int ct = 0; ct < 8; ++ct) {
    const int ft = w * 8 + ct;
    ushort4 v;
    v.x = f2bf(acc[ct][0]); v.y = f2bf(acc[ct][1]);
    v.z = f2bf(acc[ct][2]); v.w = f2bf(acc[ct][3]);
    *reinterpret_cast<ushort4*>(
        &XWf[((size_t)(t * 8 + bg) * 64 + ft) * 256 + lane * 4]) = v;
  }
}

// ---------------------------------------------------------------------------
// Phase A: 64-step LSTM scan. 8 blocks x 16 batches, 512 thr (8 waves).
// Wave w owns hidden units m in [32w,32w+32) across all 4 gates -> gates are
// lane-local in MFMA acc. acc-init comes from XWf (x@W+b precomputed).
// ONE barrier per step: Hs and Cs both double-buffered, so waves 4-7 run
// ahead into step t+1's U-streaming while waves 0-3 compute q_t.
// Emits QS[t][b][s] for Phase B.
// ---------------------------------------------------------------------------
__global__ __launch_bounds__(512, 2) void k_lstm(
    const float* __restrict__ h0, const float* __restrict__ c0,
    const float* __restrict__ w2b, const u16* __restrict__ Ut,
    const u16* __restrict__ w2t, const u16* __restrict__ XWf,
    float* __restrict__ QS) {
  __shared__ u16 Hs[2][16][264];  // h ping-pong (pad 256->264)
  __shared__ u16 Cs[2][16][264];  // c2 ping-pong

  const int tid = threadIdx.x;
  const int lane = tid & 63;
  const int w = tid >> 6;   // wave 0..7
  const int l15 = lane & 15;
  const int l4 = lane >> 4; // 0..3
  const int bg = blockIdx.x;
  const int b0 = bg << 4;

  // Stage h_0 (all 512 threads: 16 rows x 32 chunks of 8)
  {
    int row = tid >> 5, hb = (tid & 31) * 8;
    const float4* p =
        reinterpret_cast<const float4*>(&h0[(size_t)(b0 + row) * 256 + hb]);
    float4 a0 = p[0], a1 = p[1];
    *reinterpret_cast<short8*>(&Hs[0][row][hb]) = pack8(a0, a1);
  }

  // c state fp32 in registers: lane owns (batch=l4*4+r, m=32w+16n+l15)
  float creg[2][4];
#pragma unroll
  for (int n = 0; n < 2; ++n)
#pragma unroll
    for (int r = 0; r < 4; ++r)
      creg[n][r] = c0[(size_t)(b0 + l4 * 4 + r) * 256 + w * 32 + n * 16 + l15];

  float w2bv = (w < 4) ? w2b[w * 16 + l15] : 0.f;

  __syncthreads();

  for (int t = 0; t < 64; ++t) {
    const int cur = t & 1, nxt = cur ^ 1;

    // acc init = x_t@W + b (from XWf fragments)
    f32x4 acc[4][2];
#pragma unroll
    for (int g = 0; g < 4; ++g)
#pragma unroll
      for (int n = 0; n < 2; ++n) {
        const int ft = g * 16 + w * 2 + n;
        ushort4 v = *reinterpret_cast<const ushort4*>(
            &XWf[((size_t)(t * 8 + bg) * 64 + ft) * 256 + lane * 4]);
        acc[g][n] = (f32x4){bf2f(v.x), bf2f(v.y), bf2f(v.z), bf2f(v.w)};
      }

    // z += h @ U  (MFMA, K=256)
#pragma unroll
    for (int kk = 0; kk < 8; ++kk) {
      short8 af =
          *reinterpret_cast<const short8*>(&Hs[cur][l15][kk * 32 + l4 * 8]);
#pragma unroll
      for (int g = 0; g < 4; ++g)
#pragma unroll
        for (int n = 0; n < 2; ++n) {
          const int col = g * 256 + w * 32 + n * 16 + l15;
          short8 bf = *reinterpret_cast<const short8*>(
              &Ut[(size_t)col * 256 + kk * 32 + l4 * 8]);
          acc[g][n] =
              __builtin_amdgcn_mfma_f32_16x16x32_bf16(af, bf, acc[g][n], 0, 0, 0);
        }
    }

    // Gates (lane-local), update c, write h2/c2 bf16 for next step / q
#pragma unroll
    for (int n = 0; n < 2; ++n)
#pragma unroll
      for (int r = 0; r < 4; ++r) {
        float iv = sigm(acc[0][n][r]);
        float fv = sigm(acc[1][n][r]);
        float gv = tanh_(acc[2][n][r]);
        float ov = sigm(acc[3][n][r]);
        float c2 = fv * creg[n][r] + iv * gv;
        creg[n][r] = c2;
        float h2 = ov * tanh_(c2);
        int m = w * 32 + n * 16 + l15;
        int br = l4 * 4 + r;
        Hs[nxt][br][m] = f2bf(h2);
        Cs[nxt][br][m] = f2bf(c2);
      }
    __syncthreads();  // the ONLY barrier per step

    if (w < 4) {
      // q = [h2|c2] @ w2_k + w2_b  -> QS[t]   (waves 4-7 run ahead to t+1)
      f32x4 qa = (f32x4){w2bv, w2bv, w2bv, w2bv};
      const int colq = w * 16 + l15;
#pragma unroll
      for (int kk = 0; kk < 16; ++kk) {
        short8 af;
        if (kk < 8)
          af = *reinterpret_cast<const short8*>(
              &Hs[nxt][l15][kk * 32 + l4 * 8]);
        else
          af = *reinterpret_cast<const short8*>(
              &Cs[nxt][l15][(kk - 8) * 32 + l4 * 8]);
        short8 bf = *reinterpret_cast<const short8*>(
            &w2t[colq * 512 + kk * 32 + l4 * 8]);
        qa = __builtin_amdgcn_mfma_f32_16x16x32_bf16(af, bf, qa, 0, 0, 0);
      }
#pragma unroll
      for (int r = 0; r < 4; ++r)
        QS[(size_t)(t * 128 + b0 + l4 * 4 + r) * 64 + w * 16 + l15] = qa[r];
    }
  }
}

// ---------------------------------------------------------------------------
// Phase B: attention, fully parallel. Block = (batch b, t-half); 256 threads.
// Computes w1x[b] once in LDS, then 32 t's (2 at a time).
// Output scramble: out_flat[P*128+f] = data_flat[P*128+f]*alpha(t,b),
// P = t*128 + b  (exactly the reference's reshape(-1,T,n) flat identity).
// ---------------------------------------------------------------------------
__global__ __launch_bounds__(256) void k_attn(
    const float* __restrict__ data, const float* __restrict__ w1k,
    const float* __restrict__ w1b, const float* __restrict__ vk,
    const float* __restrict__ vb, const float* __restrict__ QS,
    float* __restrict__ out) {
  __shared__ float Xs[64][128];   // data[b]
  __shared__ float Wk[64][64];    // w1_k
  __shared__ float w1x[128][67];  // w1x[b][f][s] (+w1_b), pad 67 (3 mod 32)
  __shared__ float vls[64];
  __shared__ float qls[2][64];
  __shared__ float red[4][2];

  const int tid = threadIdx.x;
  const int b = blockIdx.x >> 1;
  const int half = blockIdx.x & 1;

#pragma unroll
  for (int c = 0; c < 8; ++c) {
    int i = c * 1024 + tid * 4;
    *reinterpret_cast<float4*>(&Xs[0][0] + i) =
        *reinterpret_cast<const float4*>(&data[(size_t)b * 8192 + i]);
  }
#pragma unroll
  for (int c = 0; c < 4; ++c) {
    int i = c * 1024 + tid * 4;
    *reinterpret_cast<float4*>(&Wk[0][0] + i) =
        *reinterpret_cast<const float4*>(&w1k[i]);
  }
  if (tid < 64) vls[tid] = vk[tid];
  __syncthreads();

  const int f = tid & 127;
  const int sh = tid >> 7;  // which of the 2 concurrent t's
  const int s0 = sh * 32;
  {
    float a[32];
#pragma unroll
    for (int j = 0; j < 32; ++j) a[j] = w1b[s0 + j];
    for (int t = 0; t < 64; ++t) {
      float xv = Xs[t][f];
#pragma unroll
      for (int j = 0; j < 32; ++j) a[j] = __fmaf_rn(xv, Wk[t][s0 + j], a[j]);
    }
#pragma unroll
    for (int j = 0; j < 32; ++j) w1x[f][s0 + j] = a[j];
  }
  __syncthreads();

  const float vbv = vb[0];
  const int wv = tid >> 6;
  const int lane = tid & 63;

  for (int tt = 0; tt < 16; ++tt) {
    if (tid < 128) {
      int which = tid >> 6, s = tid & 63;
      qls[which][s] =
          QS[(size_t)((half * 32 + tt * 2 + which) * 128 + b) * 64 + s];
    }
    __syncthreads();

    float acc = vbv;
#pragma unroll 8
    for (int s = 0; s < 64; ++s)
      acc += tanh_(w1x[f][s] + qls[sh][s]) * vls[s];

    // softmax over f within the 128-thread t-group (2 waves)
    float m = acc;
#pragma unroll
    for (int o = 32; o > 0; o >>= 1) m = fmaxf(m, __shfl_xor(m, o));
    if (lane == 0) red[wv][0] = m;
    __syncthreads();
    m = fmaxf(red[sh * 2][0], red[sh * 2 + 1][0]);
    float e = __expf(acc - m);
    float sum = e;
#pragma unroll
    for (int o = 32; o > 0; o >>= 1) sum += __shfl_xor(sum, o);
    if (lane == 0) red[wv][1] = sum;
    __syncthreads();
    sum = red[sh * 2][1] + red[sh * 2 + 1][1];
    float alpha = e / sum;

    int t = half * 32 + tt * 2 + sh;
    size_t P = (size_t)t * 128 + b;
    out[P * 128 + f] = data[P * 128 + f] * alpha;
    __syncthreads();
  }
}

// ---------------------------------------------------------------------------
extern "C" void kernel_launch(void* const* d_in, const int* in_sizes, int n_in,
                              void* d_out, int out_size, void* d_ws,
                              size_t ws_size, hipStream_t stream) {
  (void)in_sizes; (void)n_in; (void)out_size; (void)ws_size;
  const float* data = (const float*)d_in[0];
  const float* h0   = (const float*)d_in[1];
  const float* c0   = (const float*)d_in[2];
  const float* W    = (const float*)d_in[3];
  const float* U    = (const float*)d_in[4];
  const float* bias = (const float*)d_in[5];
  const float* w1k  = (const float*)d_in[6];
  const float* w1b  = (const float*)d_in[7];
  const float* w2k  = (const float*)d_in[8];
  const float* w2b  = (const float*)d_in[9];
  const float* vk   = (const float*)d_in[10];
  const float* vb   = (const float*)d_in[11];
  float* out = (float*)d_out;

  char* ws = (char*)d_ws;
  float* QS = (float*)(ws);                    //  2 MB
  u16* Ut   = (u16*)(ws + (2u << 20));         // 512 KB
  u16* Wt   = (u16*)(ws + (2u << 20) + 524288);// 256 KB
  u16* w2t  = (u16*)(ws + (2u << 20) + 786432);//  64 KB
  u16* XWf  = (u16*)(ws + (3u << 20));         // 16 MB  (total ~19 MB)

  k_prep<<<512, 256, 0, stream>>>(W, U, w2k, Wt, Ut, w2t);
  k_xw<<<512, 512, 0, stream>>>(data, bias, Wt, XWf);
  k_lstm<<<8, 512, 0, stream>>>(h0, c0, w2b, Ut, w2t, XWf, QS);
  k_attn<<<256, 256, 0, stream>>>(data, w1k, w1b, vk, vb, QS, out);
}